// Round 1
// baseline (308.150 us; speedup 1.0000x reference)
//
#include <hip/hip_runtime.h>

// Sizes (fixed by the reference)
#define NN 32
#define CC 64
#define TT 300
#define VV 25
#define KK 3
#define OO 64
#define TC 4                 // time steps per block
#define SS (TC * VV)         // 100 spatial positions per block
#define XROW 28              // padded joint stride (V=25 -> 28, keeps 16B align + banks clean)
#define XCSTRIDE (TC * XROW) // 112 floats per channel row

__global__ __launch_bounds__(128) void zero_stats(float* stats) {
    stats[threadIdx.x] = 0.0f; // 128 floats: [0..63]=sum, [64..127]=sumsq
}

__global__ __launch_bounds__(256) void gcn_main(const float* __restrict__ x,
                                                const float* __restrict__ A,
                                                const float* __restrict__ W,
                                                float* __restrict__ ypre,
                                                float* __restrict__ stats) {
    __shared__ float x_s[CC * XCSTRIDE];   // 28672 B
    __shared__ float A_s[KK * VV * XROW];  // 8400 B

    const int bid = blockIdx.x;
    const int n   = bid / (TT / TC);
    const int t0  = (bid % (TT / TC)) * TC;
    const int tid = threadIdx.x;

    // ---- stage x[n, :, t0:t0+TC, :] into LDS (coalesced: 100-float runs per channel)
    const float* xg = x + (size_t)n * CC * TT * VV + (size_t)t0 * VV;
    for (int idx = tid; idx < CC * SS; idx += 256) {
        int c = idx / SS, s = idx % SS;
        int tt = s / VV, v = s % VV;
        x_s[c * XCSTRIDE + tt * XROW + v] = xg[c * TT * VV + s];
    }
    // ---- stage A into LDS (rows padded to 28)
    for (int idx = tid; idx < KK * VV * VV; idx += 256) {
        int k = idx / (VV * VV), r = idx % (VV * VV);
        int v = r / VV, w = r % VV;
        A_s[k * VV * XROW + v * XROW + w] = A[idx];
    }
    __syncthreads();

    const int o  = tid >> 2;  // output channel (0..63)
    const int sq = tid & 3;   // time step within tile (0..3)

    float yacc[VV];
#pragma unroll
    for (int j = 0; j < VV; ++j) yacc[j] = 0.0f;

    for (int k = 0; k < KK; ++k) {
        // z[v] = sum_c W[k,o,c] * x[c, t0+sq, v]   (channel projection first)
        float z[VV];
#pragma unroll
        for (int j = 0; j < VV; ++j) z[j] = 0.0f;

        const float* Wk   = W + ((size_t)k * OO + o) * CC;
        const float* xrow = x_s + sq * XROW;
#pragma unroll 8
        for (int c = 0; c < CC; ++c) {
            float wv = Wk[c];  // L1-resident, amortized over 25 FMAs
            const float* xr = xrow + c * XCSTRIDE;
#pragma unroll
            for (int j = 0; j < VV; ++j) z[j] += wv * xr[j];
        }

        // yacc[w] += sum_v z[v] * A[k,v,w]   (graph aggregation, A broadcast from LDS)
        const float* Ak = A_s + k * VV * XROW;
#pragma unroll
        for (int v = 0; v < VV; ++v) {
            float zv = z[v];
            const float* Ar = Ak + v * XROW;
#pragma unroll
            for (int w = 0; w < VV; ++w) yacc[w] += zv * Ar[w];
        }
    }
    // NOTE: per-branch bias b.sum(0) is a per-channel constant -> exactly cancelled
    // by training-mode BN (shifts the batch mean by itself). Skipped on purpose.

    // ---- write pre-BN y and accumulate per-channel stats
    float* yg = ypre + (((size_t)n * OO + o) * TT + t0 + sq) * VV;
    float s1 = 0.0f, s2 = 0.0f;
#pragma unroll
    for (int j = 0; j < VV; ++j) {
        float v = yacc[j];
        s1 += v;
        s2 += v * v;
        yg[j] = v;
    }
    // quad reduce across the 4 threads (same o, sq=0..3 are adjacent lanes)
    s1 += __shfl_xor(s1, 1);
    s1 += __shfl_xor(s1, 2);
    s2 += __shfl_xor(s2, 1);
    s2 += __shfl_xor(s2, 2);
    if (sq == 0) {
        atomicAdd(&stats[o], s1);
        atomicAdd(&stats[OO + o], s2);
    }
}

__global__ __launch_bounds__(256) void bn_relu(float* __restrict__ y,
                                               const float* __restrict__ stats,
                                               const float* __restrict__ gamma,
                                               const float* __restrict__ beta) {
    const int i4 = blockIdx.x * 256 + threadIdx.x;  // 3,840,000 threads, 4 elems each
    const size_t i = (size_t)i4 * 4;
    // TT*VV = 7500 is divisible by 4 -> each float4 group is within one channel o
    const int o = (int)((i / (TT * VV)) % OO);

    const float cnt  = (float)NN * TT * VV;  // 240000
    const float mean = stats[o] / cnt;
    const float var  = stats[OO + o] / cnt - mean * mean;
    const float inv  = rsqrtf(var + 1e-5f);
    const float sc   = gamma[o] * inv;
    const float sh   = beta[o] - mean * sc;

    float4 v = *reinterpret_cast<float4*>(y + i);
    v.x = fmaxf(v.x * sc + sh, 0.0f);
    v.y = fmaxf(v.y * sc + sh, 0.0f);
    v.z = fmaxf(v.z * sc + sh, 0.0f);
    v.w = fmaxf(v.w * sc + sh, 0.0f);
    *reinterpret_cast<float4*>(y + i) = v;
}

extern "C" void kernel_launch(void* const* d_in, const int* in_sizes, int n_in,
                              void* d_out, int out_size, void* d_ws, size_t ws_size,
                              hipStream_t stream) {
    const float* x     = (const float*)d_in[0];
    const float* A     = (const float*)d_in[1];
    const float* W     = (const float*)d_in[2];
    // d_in[3] = b : exactly cancelled by training-mode BN, unused
    const float* gamma = (const float*)d_in[4];
    const float* beta  = (const float*)d_in[5];
    float* out   = (float*)d_out;
    float* stats = (float*)d_ws;  // 128 floats of scratch

    hipLaunchKernelGGL(zero_stats, dim3(1), dim3(128), 0, stream, stats);
    hipLaunchKernelGGL(gcn_main, dim3(NN * (TT / TC)), dim3(256), 0, stream,
                       x, A, W, out, stats);
    hipLaunchKernelGGL(bn_relu, dim3((NN * OO * TT * VV) / 4 / 256), dim3(256), 0, stream,
                       out, stats, gamma, beta);
}

// Round 2
// 180.476 us; speedup vs baseline: 1.7074x; 1.7074x over previous
//
#include <hip/hip_runtime.h>

// Sizes (fixed by the reference)
#define NN 32
#define CC 64
#define TT 300
#define VV 25
#define KK 3
#define OO 64
#define TC 4                 // time steps per block
#define SS (TC * VV)         // 100 spatial positions per block
#define XROW 28              // padded joint stride (25 -> 28: 16B-aligned rows, bank-clean)
#define XCSTRIDE (TC * XROW) // 112 floats per channel

__global__ __launch_bounds__(128) void zero_stats(float* stats) {
    stats[threadIdx.x] = 0.0f; // [0..63]=sum, [64..127]=sumsq
}

__global__ __launch_bounds__(256) void gcn_main(const float* __restrict__ x,
                                                const float* __restrict__ A,
                                                const float* __restrict__ W,
                                                float* __restrict__ ypre,
                                                float* __restrict__ stats) {
    __shared__ float x_s[CC * XCSTRIDE]; // 28672 B (A no longer staged -> more blocks/CU)

    const int bid = blockIdx.x;
    const int n   = bid / (TT / TC);
    const int t0  = (bid % (TT / TC)) * TC;
    const int tid = threadIdx.x;

    // ---- stage x[n, :, t0:t0+TC, :] into LDS, float4 global loads
    // per channel c the 100 floats x[n,c,t0*25 .. t0*25+100) are contiguous and
    // 16B-aligned (t0 % 4 == 0 -> offset 100*t0/4 float4s)
    const float* xg = x + (size_t)n * CC * TT * VV + (size_t)t0 * VV;
    for (int idx4 = tid; idx4 < CC * SS / 4; idx4 += 256) {
        int c = idx4 / (SS / 4), q = idx4 % (SS / 4);
        float4 f = *reinterpret_cast<const float4*>(xg + (size_t)c * TT * VV + q * 4);
        int s = q * 4;
        float* dst = x_s + c * XCSTRIDE;
        // scalar LDS writes (float4 may straddle the 25-joint row boundary)
        dst[(s    ) / VV * XROW + (s    ) % VV] = f.x;
        dst[(s + 1) / VV * XROW + (s + 1) % VV] = f.y;
        dst[(s + 2) / VV * XROW + (s + 2) % VV] = f.z;
        dst[(s + 3) / VV * XROW + (s + 3) % VV] = f.w;
    }
    __syncthreads();

    const int o  = tid >> 2;  // output channel (0..63)
    const int sq = tid & 3;   // time step within tile

    // ---- projection: z[k][v] = sum_c W[k,o,c] * x[c, t0+sq, v]
    // x read ONCE per c (k-hoisted: each LDS read feeds 3 FMAs)
    float z[KK][VV];
#pragma unroll
    for (int k = 0; k < KK; ++k)
#pragma unroll
        for (int j = 0; j < VV; ++j) z[k][j] = 0.0f;

    const float* Wk0  = W + ((size_t)0 * OO + o) * CC;
    const float* Wk1  = W + ((size_t)1 * OO + o) * CC;
    const float* Wk2  = W + ((size_t)2 * OO + o) * CC;
    const float* xrow = x_s + sq * XROW;

#pragma unroll 2
    for (int c = 0; c < CC; ++c) {
        const float* xp = xrow + c * XCSTRIDE;
        float xr[VV];
#pragma unroll
        for (int j = 0; j < VV; ++j) xr[j] = xp[j];
        float w0 = Wk0[c], w1 = Wk1[c], w2 = Wk2[c];
#pragma unroll
        for (int j = 0; j < VV; ++j) {
            z[0][j] = fmaf(w0, xr[j], z[0][j]);
            z[1][j] = fmaf(w1, xr[j], z[1][j]);
            z[2][j] = fmaf(w2, xr[j], z[2][j]);
        }
    }

    // ---- aggregation: yacc[w] = sum_k sum_v z[k][v] * A[k,v,w]
    // A address is wave-uniform -> scalar loads (s_load), off the LDS pipe
    float yacc[VV];
#pragma unroll
    for (int j = 0; j < VV; ++j) yacc[j] = 0.0f;

#pragma unroll
    for (int k = 0; k < KK; ++k) {
#pragma unroll
        for (int v = 0; v < VV; ++v) {
            float zv = z[k][v];
            const float* Ar = A + ((size_t)k * VV + v) * VV;
#pragma unroll
            for (int w = 0; w < VV; ++w) yacc[w] = fmaf(zv, Ar[w], yacc[w]);
        }
    }
    // NOTE: per-branch bias b.sum(0) is a per-channel constant -> exactly
    // cancelled by training-mode BN. Skipped on purpose (exact).

    // ---- write pre-BN y and accumulate per-channel stats
    float* yg = ypre + (((size_t)n * OO + o) * TT + t0 + sq) * VV;
    float s1 = 0.0f, s2 = 0.0f;
#pragma unroll
    for (int j = 0; j < VV; ++j) {
        float v = yacc[j];
        s1 += v;
        s2 += v * v;
        yg[j] = v;
    }
    s1 += __shfl_xor(s1, 1);
    s1 += __shfl_xor(s1, 2);
    s2 += __shfl_xor(s2, 1);
    s2 += __shfl_xor(s2, 2);
    if (sq == 0) {
        atomicAdd(&stats[o], s1);
        atomicAdd(&stats[OO + o], s2);
    }
}

__global__ __launch_bounds__(256) void bn_relu(float* __restrict__ y,
                                               const float* __restrict__ stats,
                                               const float* __restrict__ gamma,
                                               const float* __restrict__ beta) {
    const int i4 = blockIdx.x * 256 + threadIdx.x;
    const size_t i = (size_t)i4 * 4;
    const int o = (int)((i / (TT * VV)) % OO);  // TT*VV=7500 divisible by 4

    const float cnt  = (float)NN * TT * VV;
    const float mean = stats[o] / cnt;
    const float var  = stats[OO + o] / cnt - mean * mean;
    const float inv  = rsqrtf(var + 1e-5f);
    const float sc   = gamma[o] * inv;
    const float sh   = beta[o] - mean * sc;

    float4 v = *reinterpret_cast<float4*>(y + i);
    v.x = fmaxf(v.x * sc + sh, 0.0f);
    v.y = fmaxf(v.y * sc + sh, 0.0f);
    v.z = fmaxf(v.z * sc + sh, 0.0f);
    v.w = fmaxf(v.w * sc + sh, 0.0f);
    *reinterpret_cast<float4*>(y + i) = v;
}

extern "C" void kernel_launch(void* const* d_in, const int* in_sizes, int n_in,
                              void* d_out, int out_size, void* d_ws, size_t ws_size,
                              hipStream_t stream) {
    const float* x     = (const float*)d_in[0];
    const float* A     = (const float*)d_in[1];
    const float* W     = (const float*)d_in[2];
    // d_in[3] = b : exactly cancelled by training-mode BN, unused
    const float* gamma = (const float*)d_in[4];
    const float* beta  = (const float*)d_in[5];
    float* out   = (float*)d_out;
    float* stats = (float*)d_ws;

    hipLaunchKernelGGL(zero_stats, dim3(1), dim3(128), 0, stream, stats);
    hipLaunchKernelGGL(gcn_main, dim3(NN * (TT / TC)), dim3(256), 0, stream,
                       x, A, W, out, stats);
    hipLaunchKernelGGL(bn_relu, dim3((NN * OO * TT * VV) / 4 / 256), dim3(256), 0, stream,
                       out, stats, gamma, beta);
}

// Round 3
// 170.264 us; speedup vs baseline: 1.8098x; 1.0600x over previous
//
#include <hip/hip_runtime.h>

// Sizes (fixed by the reference)
#define NN 32
#define CC 64
#define TT 300
#define VV 25
#define KK 3
#define OO 64
#define TC 4                 // time steps per block
#define SS (TC * VV)         // 100 spatial positions per block
#define XROW 28              // padded joint stride: 112B rows -> every (c,sq) row 16B-aligned
#define XCSTRIDE (TC * XROW) // 112 floats per channel

__global__ __launch_bounds__(128) void zero_stats(float* stats) {
    stats[threadIdx.x] = 0.0f; // [0..63]=sum, [64..127]=sumsq
}

__global__ __launch_bounds__(256, 4) void gcn_main(const float* __restrict__ x,
                                                   const float* __restrict__ A,
                                                   const float* __restrict__ W,
                                                   float* __restrict__ ypre,
                                                   float* __restrict__ stats) {
    __shared__ float x_s[CC * XCSTRIDE]; // 28672 B -> 5 blocks/CU by LDS

    const int bid = blockIdx.x;
    const int n   = bid / (TT / TC);
    const int t0  = (bid % (TT / TC)) * TC;
    const int tid = threadIdx.x;

    // ---- stage x[n, :, t0:t0+TC, :] into LDS (float4 global loads, contiguous
    // 100-float run per channel, 16B-aligned since t0*25*4 % 16 == 0)
    const float* xg = x + (size_t)n * CC * TT * VV + (size_t)t0 * VV;
    for (int idx4 = tid; idx4 < CC * SS / 4; idx4 += 256) {
        int c = idx4 / (SS / 4), q = idx4 % (SS / 4);
        float4 f = *reinterpret_cast<const float4*>(xg + (size_t)c * TT * VV + q * 4);
        int s = q * 4;
        float* dst = x_s + c * XCSTRIDE;
        dst[(s    ) / VV * XROW + (s    ) % VV] = f.x;
        dst[(s + 1) / VV * XROW + (s + 1) % VV] = f.y;
        dst[(s + 2) / VV * XROW + (s + 2) % VV] = f.z;
        dst[(s + 3) / VV * XROW + (s + 3) % VV] = f.w;
    }
    __syncthreads();

    const int o  = tid >> 2;  // output channel (0..63)
    const int sq = tid & 3;   // time step within tile
    const float* xrow = x_s + sq * XROW;  // lanes w/ same sq broadcast (free in LDS)

    float yacc[VV];
#pragma unroll
    for (int j = 0; j < VV; ++j) yacc[j] = 0.0f;

    // Per-k pass: z[25] lives only inside one iteration -> register-resident.
    // x is re-read from LDS each k, but those reads are 4-address broadcasts (cheap).
#pragma unroll 1
    for (int k = 0; k < KK; ++k) {
        float z[VV];
#pragma unroll
        for (int j = 0; j < VV; ++j) z[j] = 0.0f;

        const float4* Wp = reinterpret_cast<const float4*>(W + ((size_t)k * OO + o) * CC);
#pragma unroll 4
        for (int c4 = 0; c4 < CC / 4; ++c4) {
            float4 wv = Wp[c4];  // 16 float4 loads per pass, L2-resident
            const float* xp = xrow + (c4 * 4) * XCSTRIDE;
#pragma unroll
            for (int j = 0; j < VV; ++j) z[j] = fmaf(wv.x, xp[j], z[j]);
            xp += XCSTRIDE;
#pragma unroll
            for (int j = 0; j < VV; ++j) z[j] = fmaf(wv.y, xp[j], z[j]);
            xp += XCSTRIDE;
#pragma unroll
            for (int j = 0; j < VV; ++j) z[j] = fmaf(wv.z, xp[j], z[j]);
            xp += XCSTRIDE;
#pragma unroll
            for (int j = 0; j < VV; ++j) z[j] = fmaf(wv.w, xp[j], z[j]);
        }

        // aggregate into yacc before z goes dead; A is wave-uniform -> scalar loads
        const float* Ak = A + (size_t)k * VV * VV;
#pragma unroll
        for (int v = 0; v < VV; ++v) {
            float zv = z[v];
            const float* Ar = Ak + v * VV;
#pragma unroll
            for (int w = 0; w < VV; ++w) yacc[w] = fmaf(zv, Ar[w], yacc[w]);
        }
    }
    // NOTE: per-branch bias b.sum(0) is a per-channel constant -> exactly
    // cancelled by training-mode BN. Skipped on purpose (exact).

    // ---- write pre-BN y and accumulate per-channel stats
    float* yg = ypre + (((size_t)n * OO + o) * TT + t0 + sq) * VV;
    float s1 = 0.0f, s2 = 0.0f;
#pragma unroll
    for (int j = 0; j < VV; ++j) {
        float v = yacc[j];
        s1 += v;
        s2 += v * v;
        yg[j] = v;
    }
    s1 += __shfl_xor(s1, 1);
    s1 += __shfl_xor(s1, 2);
    s2 += __shfl_xor(s2, 1);
    s2 += __shfl_xor(s2, 2);
    if (sq == 0) {
        atomicAdd(&stats[o], s1);
        atomicAdd(&stats[OO + o], s2);
    }
}

__global__ __launch_bounds__(256) void bn_relu(float* __restrict__ y,
                                               const float* __restrict__ stats,
                                               const float* __restrict__ gamma,
                                               const float* __restrict__ beta) {
    const int i4 = blockIdx.x * 256 + threadIdx.x;
    const size_t i = (size_t)i4 * 4;
    const int o = (int)((i / (TT * VV)) % OO);  // TT*VV=7500 divisible by 4

    const float cnt  = (float)NN * TT * VV;
    const float mean = stats[o] / cnt;
    const float var  = stats[OO + o] / cnt - mean * mean;
    const float inv  = rsqrtf(var + 1e-5f);
    const float sc   = gamma[o] * inv;
    const float sh   = beta[o] - mean * sc;

    float4 v = *reinterpret_cast<float4*>(y + i);
    v.x = fmaxf(v.x * sc + sh, 0.0f);
    v.y = fmaxf(v.y * sc + sh, 0.0f);
    v.z = fmaxf(v.z * sc + sh, 0.0f);
    v.w = fmaxf(v.w * sc + sh, 0.0f);
    *reinterpret_cast<float4*>(y + i) = v;
}

extern "C" void kernel_launch(void* const* d_in, const int* in_sizes, int n_in,
                              void* d_out, int out_size, void* d_ws, size_t ws_size,
                              hipStream_t stream) {
    const float* x     = (const float*)d_in[0];
    const float* A     = (const float*)d_in[1];
    const float* W     = (const float*)d_in[2];
    // d_in[3] = b : exactly cancelled by training-mode BN, unused
    const float* gamma = (const float*)d_in[4];
    const float* beta  = (const float*)d_in[5];
    float* out   = (float*)d_out;
    float* stats = (float*)d_ws;

    hipLaunchKernelGGL(zero_stats, dim3(1), dim3(128), 0, stream, stats);
    hipLaunchKernelGGL(gcn_main, dim3(NN * (TT / TC)), dim3(256), 0, stream,
                       x, A, W, out, stats);
    hipLaunchKernelGGL(bn_relu, dim3((NN * OO * TT * VV) / 4 / 256), dim3(256), 0, stream,
                       out, stats, gamma, beta);
}

// Round 4
// 159.155 us; speedup vs baseline: 1.9362x; 1.0698x over previous
//
#include <hip/hip_runtime.h>

// Sizes (fixed by the reference)
#define NN 32
#define CC 64
#define TT 300
#define VV 25
#define KK 3
#define OO 64
#define TB 4          // time steps per block
#define SB (TB * VV)  // 100 output spatial positions per block

typedef __attribute__((ext_vector_type(8))) short short8;  // 8 bf16 = 4 VGPR
typedef __attribute__((ext_vector_type(4))) float f32x4;

// f32 -> bf16, round-to-nearest-even
__device__ __forceinline__ unsigned short f2bf(float f) {
    unsigned u = __builtin_bit_cast(unsigned, f);
    u += 0x7FFFu + ((u >> 16) & 1u);
    return (unsigned short)(u >> 16);
}

__global__ __launch_bounds__(128) void zero_stats(float* stats) {
    stats[threadIdx.x] = 0.0f;  // [0..63]=sum, [64..127]=sumsq
}

// Block: (n, 4 time steps). 512 threads = 8 waves.
// Phase A: stage x[n,:,t0:t0+4,:] -> bf16 LDS x_s[row=t*64+c][v pad32] (swizzled)
// Phase B: GEMM1 (MFMA 16x16x32): xa[(t,c),w] = sum_v x*A_k  -> xa_s[s=t*25+w][kc=k*64+c]
// Phase C: GEMM2 (MFMA 16x16x32): y[o,s] = sum_kc W'[o,kc]*xa[kc,s] -> global + stats
__global__ __launch_bounds__(512, 4) void gcn_main(const float* __restrict__ x,
                                                   const float* __restrict__ A,
                                                   const float* __restrict__ W,
                                                   float* __restrict__ ypre,
                                                   float* __restrict__ stats) {
    __shared__ alignas(16) unsigned short x_s[256 * 32];    // 16 KB
    __shared__ alignas(16) unsigned short xa_s[112 * 192];  // 42 KB (rows 100..111 = N-pad, never stored)
    __shared__ float stats_s[128];

    const int bid  = blockIdx.x;
    const int n    = bid / (TT / TB);
    const int t0   = (bid % (TT / TB)) * TB;
    const int tid  = threadIdx.x;
    const int lane = tid & 63;
    const int wid  = tid >> 6;
    const int li   = lane & 15;   // fragment row/col index
    const int g    = lane >> 4;   // 16-lane group: k-elems = 8g..8g+7

    if (tid < 128) stats_s[tid] = 0.0f;

    // ---- Phase A: stage x (coalesced float4 global, scalar bf16 LDS writes)
    const float* xg = x + (size_t)n * (CC * TT * VV) + (size_t)t0 * VV;
    for (int idx = tid; idx < CC * 25; idx += 512) {  // 1600 float4 = 100 f32 per channel
        int c = idx / 25, q = idx - c * 25;
        const float4 f = *reinterpret_cast<const float4*>(xg + (size_t)c * (TT * VV) + q * 4);
        float vals[4] = {f.x, f.y, f.z, f.w};
        int s0 = q * 4;
#pragma unroll
        for (int i = 0; i < 4; ++i) {
            int sp = s0 + i;               // may straddle the 25-joint boundary
            int t = sp / 25, v = sp - t * 25;
            int row = t * 64 + c;
            x_s[row * 32 + (v ^ (((row >> 1) & 3) << 3))] = f2bf(vals[i]);
        }
    }
    for (int idx = tid; idx < 256 * 7; idx += 512) {  // zero-fill K-pad v=25..31
        int row = idx / 7, v = 25 + (idx - row * 7);
        x_s[row * 32 + (v ^ (((row >> 1) & 3) << 3))] = 0;
    }

    // ---- A_k^T B-fragments (registers; col w = li, k-elems v = 8g+e; pad -> 0)
    short8 afrag[6];
#pragma unroll
    for (int k = 0; k < KK; ++k) {
#pragma unroll
        for (int nt = 0; nt < 2; ++nt) {
            int w = nt * 16 + li;
            short8 fr;
#pragma unroll
            for (int e = 0; e < 8; ++e) {
                int v = g * 8 + e;
                float val = (v < VV && w < VV) ? A[(k * VV + v) * VV + w] : 0.0f;
                fr[e] = (short)f2bf(val);
            }
            afrag[k * 2 + nt] = fr;
        }
    }

    __syncthreads();

    // ---- Phase B: GEMM1. M=(t*64+c) 256 rows = 16 Mtiles, N=w (2 tiles), K=32 (one MFMA)
    // k kept STATIC (afrag indexing must be compile-time -> no scratch, rule #20)
#pragma unroll
    for (int k = 0; k < KK; ++k) {
        for (int mt = wid; mt < 16; mt += 8) {  // 2 Mtiles per wave per k
            int row = mt * 16 + li;
            const short8 xf = *reinterpret_cast<const short8*>(
                &x_s[row * 32 + ((g * 8) ^ (((row >> 1) & 3) << 3))]);
            f32x4 acc0 = {0.f, 0.f, 0.f, 0.f}, acc1 = {0.f, 0.f, 0.f, 0.f};
            acc0 = __builtin_amdgcn_mfma_f32_16x16x32_bf16(xf, afrag[k * 2 + 0], acc0, 0, 0, 0);
            acc1 = __builtin_amdgcn_mfma_f32_16x16x32_bf16(xf, afrag[k * 2 + 1], acc1, 0, 0, 0);
            // C-frag: col=li (w), rows = mt*16 + 4g + j  ->  t = row>>6, c-quad = row&63
            int r0 = mt * 16 + g * 4;
            int t = r0 >> 6, c0 = r0 & 63;
            int kc = k * 64 + c0;
            {
                int s = t * 25 + li;  // w = li < 25 always valid for tile 0? (li<16<25 yes)
                unsigned long long p =
                    (unsigned long long)f2bf(acc0[0]) |
                    ((unsigned long long)f2bf(acc0[1]) << 16) |
                    ((unsigned long long)f2bf(acc0[2]) << 32) |
                    ((unsigned long long)f2bf(acc0[3]) << 48);
                *reinterpret_cast<unsigned long long*>(
                    &xa_s[s * 192 + (kc ^ ((s & 7) << 3))]) = p;
            }
            int w1 = 16 + li;
            if (w1 < VV) {
                int s = t * 25 + w1;
                unsigned long long p =
                    (unsigned long long)f2bf(acc1[0]) |
                    ((unsigned long long)f2bf(acc1[1]) << 16) |
                    ((unsigned long long)f2bf(acc1[2]) << 32) |
                    ((unsigned long long)f2bf(acc1[3]) << 48);
                *reinterpret_cast<unsigned long long*>(
                    &xa_s[s * 192 + (kc ^ ((s & 7) << 3))]) = p;
            }
        }
    }

    __syncthreads();

    // ---- Phase C: GEMM2. M=o (4 Mtiles), N=s (7 Ntiles, last ragged), K=192 (6 steps)
    for (int u = wid; u < 28; u += 8) {
        int mt = u / 7, nt = u - mt * 7;
        int o = mt * 16 + li;          // A-frag row
        int srow = nt * 16 + li;       // B-frag col = xa_s row
        f32x4 y = {0.f, 0.f, 0.f, 0.f};
#pragma unroll
        for (int kap = 0; kap < 6; ++kap) {
            int k = kap >> 1;
            int cb = (kap & 1) * 32 + g * 8;
            const float* wp = W + ((size_t)(k * OO + o)) * CC + cb;
            float4 wa = *reinterpret_cast<const float4*>(wp);
            float4 wb = *reinterpret_cast<const float4*>(wp + 4);
            short8 wf;
            wf[0] = (short)f2bf(wa.x); wf[1] = (short)f2bf(wa.y);
            wf[2] = (short)f2bf(wa.z); wf[3] = (short)f2bf(wa.w);
            wf[4] = (short)f2bf(wb.x); wf[5] = (short)f2bf(wb.y);
            wf[6] = (short)f2bf(wb.z); wf[7] = (short)f2bf(wb.w);
            const short8 xaf = *reinterpret_cast<const short8*>(
                &xa_s[srow * 192 + ((kap * 32 + g * 8) ^ ((srow & 7) << 3))]);
            y = __builtin_amdgcn_mfma_f32_16x16x32_bf16(wf, xaf, y, 0, 0, 0);
        }
        // epilogue: C-frag col = srow (s), rows = o-quad mt*16+4g+j  -> coalesced 64B stores
        bool sv = srow < SB;
        int oq = mt * 16 + g * 4;
        if (sv) {
            size_t base = ((size_t)n * OO + oq) * (TT * VV) + (size_t)t0 * VV + srow;
            ypre[base             ] = y[0];
            ypre[base + 1 * TT * VV] = y[1];
            ypre[base + 2 * TT * VV] = y[2];
            ypre[base + 3 * TT * VV] = y[3];
        }
        float s1[4], s2[4];
#pragma unroll
        for (int j = 0; j < 4; ++j) {
            float v = sv ? y[j] : 0.0f;
            s1[j] = v;
            s2[j] = v * v;
        }
#pragma unroll
        for (int d = 1; d < 16; d <<= 1) {
#pragma unroll
            for (int j = 0; j < 4; ++j) {
                s1[j] += __shfl_xor(s1[j], d);
                s2[j] += __shfl_xor(s2[j], d);
            }
        }
        if (li == 0) {
#pragma unroll
            for (int j = 0; j < 4; ++j) {
                atomicAdd(&stats_s[oq + j], s1[j]);
                atomicAdd(&stats_s[64 + oq + j], s2[j]);
            }
        }
    }
    // NOTE: per-branch bias b.sum(0) is a per-channel constant -> exactly
    // cancelled by training-mode BN. Skipped on purpose (exact).

    __syncthreads();
    if (tid < 128) atomicAdd(&stats[tid], stats_s[tid]);
}

__global__ __launch_bounds__(256) void bn_relu(float* __restrict__ y,
                                               const float* __restrict__ stats,
                                               const float* __restrict__ gamma,
                                               const float* __restrict__ beta) {
    const int i4 = blockIdx.x * 256 + threadIdx.x;
    const size_t i = (size_t)i4 * 4;
    const int o = (int)((i / (TT * VV)) % OO);  // TT*VV=7500 divisible by 4

    const float cnt  = (float)NN * TT * VV;
    const float mean = stats[o] / cnt;
    const float var  = stats[OO + o] / cnt - mean * mean;
    const float inv  = rsqrtf(var + 1e-5f);
    const float sc   = gamma[o] * inv;
    const float sh   = beta[o] - mean * sc;

    float4 v = *reinterpret_cast<float4*>(y + i);
    v.x = fmaxf(v.x * sc + sh, 0.0f);
    v.y = fmaxf(v.y * sc + sh, 0.0f);
    v.z = fmaxf(v.z * sc + sh, 0.0f);
    v.w = fmaxf(v.w * sc + sh, 0.0f);
    *reinterpret_cast<float4*>(y + i) = v;
}

extern "C" void kernel_launch(void* const* d_in, const int* in_sizes, int n_in,
                              void* d_out, int out_size, void* d_ws, size_t ws_size,
                              hipStream_t stream) {
    const float* x     = (const float*)d_in[0];
    const float* A     = (const float*)d_in[1];
    const float* W     = (const float*)d_in[2];
    // d_in[3] = b : exactly cancelled by training-mode BN, unused
    const float* gamma = (const float*)d_in[4];
    const float* beta  = (const float*)d_in[5];
    float* out   = (float*)d_out;
    float* stats = (float*)d_ws;

    hipLaunchKernelGGL(zero_stats, dim3(1), dim3(128), 0, stream, stats);
    hipLaunchKernelGGL(gcn_main, dim3(NN * (TT / TB)), dim3(512), 0, stream,
                       x, A, W, out, stats);
    hipLaunchKernelGGL(bn_relu, dim3((NN * OO * TT * VV) / 4 / 256), dim3(256), 0, stream,
                       out, stats, gamma, beta);
}

// Round 5
// 159.078 us; speedup vs baseline: 1.9371x; 1.0005x over previous
//
#include <hip/hip_runtime.h>

// Sizes (fixed by the reference)
#define NN 32
#define CC 64
#define TT 300
#define VV 25
#define KK 3
#define OO 64
#define TB 4          // time steps per block
#define SB (TB * VV)  // 100 output spatial positions per block
#define NREP 64       // replicated stats accumulators (kills same-line atomic serialization)
#define FINAL_OFF (NREP * 128)  // float offset of final stats within d_ws

typedef __attribute__((ext_vector_type(8))) short short8;  // 8 bf16 = 4 VGPR
typedef __attribute__((ext_vector_type(4))) float f32x4;

// f32 -> bf16, round-to-nearest-even
__device__ __forceinline__ unsigned short f2bf(float f) {
    unsigned u = __builtin_bit_cast(unsigned, f);
    u += 0x7FFFu + ((u >> 16) & 1u);
    return (unsigned short)(u >> 16);
}

__global__ __launch_bounds__(256) void zero_stats(float* ws) {
    ws[blockIdx.x * 256 + threadIdx.x] = 0.0f;  // zeroes NREP*128 = 8192 replica floats
}

// Fold 64 replicas -> final stats at ws[FINAL_OFF .. FINAL_OFF+128)
__global__ __launch_bounds__(128) void reduce_stats(float* ws) {
    const int t = threadIdx.x;
    float s = 0.0f;
#pragma unroll 8
    for (int r = 0; r < NREP; ++r) s += ws[r * 128 + t];
    ws[FINAL_OFF + t] = s;
}

// Block: (n, 4 time steps). 512 threads = 8 waves.
// Phase A: stage x[n,:,t0:t0+4,:] -> bf16 LDS x_s[row=t*64+c][v pad32] (swizzled)
// Phase B: GEMM1 (MFMA 16x16x32): xa[(t,c),w] = sum_v x*A_k  -> xa_s[s=t*25+w][kc=k*64+c]
// Phase C: GEMM2 (MFMA 16x16x32): y[o,s] = sum_kc W'[o,kc]*xa[kc,s] -> global + stats
__global__ __launch_bounds__(512, 4) void gcn_main(const float* __restrict__ x,
                                                   const float* __restrict__ A,
                                                   const float* __restrict__ W,
                                                   float* __restrict__ ypre,
                                                   float* __restrict__ ws) {
    __shared__ alignas(16) unsigned short x_s[256 * 32];    // 16 KB
    __shared__ alignas(16) unsigned short xa_s[112 * 192];  // 42 KB (rows 100..111 = N-pad garbage,
                                                            // only feeds masked-out C columns)
    __shared__ float stats_s[128];

    const int bid  = blockIdx.x;
    const int n    = bid / (TT / TB);
    const int t0   = (bid % (TT / TB)) * TB;
    const int tid  = threadIdx.x;
    const int lane = tid & 63;
    const int wid  = tid >> 6;
    const int li   = lane & 15;   // fragment row/col index
    const int g    = lane >> 4;   // 16-lane group: k-elems = 8g..8g+7

    if (tid < 128) stats_s[tid] = 0.0f;

    // ---- Phase A: stage x (coalesced float4 global, scalar bf16 LDS writes)
    const float* xg = x + (size_t)n * (CC * TT * VV) + (size_t)t0 * VV;
    for (int idx = tid; idx < CC * 25; idx += 512) {  // 1600 float4 = 100 f32 per channel
        int c = idx / 25, q = idx - c * 25;
        const float4 f = *reinterpret_cast<const float4*>(xg + (size_t)c * (TT * VV) + q * 4);
        float vals[4] = {f.x, f.y, f.z, f.w};
        int s0 = q * 4;
#pragma unroll
        for (int i = 0; i < 4; ++i) {
            int sp = s0 + i;               // may straddle the 25-joint boundary
            int t = sp / 25, v = sp - t * 25;
            int row = t * 64 + c;
            x_s[row * 32 + (v ^ (((row >> 1) & 3) << 3))] = f2bf(vals[i]);
        }
    }
    for (int idx = tid; idx < 256 * 7; idx += 512) {  // zero-fill K-pad v=25..31
        int row = idx / 7, v = 25 + (idx - row * 7);
        x_s[row * 32 + (v ^ (((row >> 1) & 3) << 3))] = 0;
    }

    // ---- A_k^T B-fragments (registers; col w = li, k-elems v = 8g+e; pad -> 0)
    short8 afrag[6];
#pragma unroll
    for (int k = 0; k < KK; ++k) {
#pragma unroll
        for (int nt = 0; nt < 2; ++nt) {
            int w = nt * 16 + li;
            short8 fr;
#pragma unroll
            for (int e = 0; e < 8; ++e) {
                int v = g * 8 + e;
                float val = (v < VV && w < VV) ? A[(k * VV + v) * VV + w] : 0.0f;
                fr[e] = (short)f2bf(val);
            }
            afrag[k * 2 + nt] = fr;
        }
    }

    __syncthreads();

    // ---- Phase B: GEMM1. M=(t*64+c) 256 rows = 16 Mtiles, N=w (2 tiles), K=32 (one MFMA)
#pragma unroll
    for (int k = 0; k < KK; ++k) {
        for (int mt = wid; mt < 16; mt += 8) {  // 2 Mtiles per wave per k
            int row = mt * 16 + li;
            const short8 xf = *reinterpret_cast<const short8*>(
                &x_s[row * 32 + ((g * 8) ^ (((row >> 1) & 3) << 3))]);
            f32x4 acc0 = {0.f, 0.f, 0.f, 0.f}, acc1 = {0.f, 0.f, 0.f, 0.f};
            acc0 = __builtin_amdgcn_mfma_f32_16x16x32_bf16(xf, afrag[k * 2 + 0], acc0, 0, 0, 0);
            acc1 = __builtin_amdgcn_mfma_f32_16x16x32_bf16(xf, afrag[k * 2 + 1], acc1, 0, 0, 0);
            // C-frag: col=li (w), rows = mt*16 + 4g + j  ->  t = row>>6, c-quad = row&63
            int r0 = mt * 16 + g * 4;
            int t = r0 >> 6, c0 = r0 & 63;
            int kc = k * 64 + c0;
            {
                int s = t * 25 + li;
                unsigned long long p =
                    (unsigned long long)f2bf(acc0[0]) |
                    ((unsigned long long)f2bf(acc0[1]) << 16) |
                    ((unsigned long long)f2bf(acc0[2]) << 32) |
                    ((unsigned long long)f2bf(acc0[3]) << 48);
                *reinterpret_cast<unsigned long long*>(
                    &xa_s[s * 192 + (kc ^ ((s & 7) << 3))]) = p;
            }
            int w1 = 16 + li;
            if (w1 < VV) {
                int s = t * 25 + w1;
                unsigned long long p =
                    (unsigned long long)f2bf(acc1[0]) |
                    ((unsigned long long)f2bf(acc1[1]) << 16) |
                    ((unsigned long long)f2bf(acc1[2]) << 32) |
                    ((unsigned long long)f2bf(acc1[3]) << 48);
                *reinterpret_cast<unsigned long long*>(
                    &xa_s[s * 192 + (kc ^ ((s & 7) << 3))]) = p;
            }
        }
    }

    __syncthreads();

    // ---- Phase C: GEMM2. M=o (4 Mtiles), N=s (7 Ntiles, last ragged), K=192 (6 steps)
    for (int u = wid; u < 28; u += 8) {
        int mt = u / 7, nt = u - mt * 7;
        int o = mt * 16 + li;          // A-frag row
        int srow = nt * 16 + li;       // B-frag col = xa_s row
        f32x4 y = {0.f, 0.f, 0.f, 0.f};
#pragma unroll
        for (int kap = 0; kap < 6; ++kap) {
            int k = kap >> 1;
            int cb = (kap & 1) * 32 + g * 8;
            const float* wp = W + ((size_t)(k * OO + o)) * CC + cb;
            float4 wa = *reinterpret_cast<const float4*>(wp);
            float4 wb = *reinterpret_cast<const float4*>(wp + 4);
            short8 wf;
            wf[0] = (short)f2bf(wa.x); wf[1] = (short)f2bf(wa.y);
            wf[2] = (short)f2bf(wa.z); wf[3] = (short)f2bf(wa.w);
            wf[4] = (short)f2bf(wb.x); wf[5] = (short)f2bf(wb.y);
            wf[6] = (short)f2bf(wb.z); wf[7] = (short)f2bf(wb.w);
            const short8 xaf = *reinterpret_cast<const short8*>(
                &xa_s[srow * 192 + ((kap * 32 + g * 8) ^ ((srow & 7) << 3))]);
            y = __builtin_amdgcn_mfma_f32_16x16x32_bf16(wf, xaf, y, 0, 0, 0);
        }
        // epilogue: C-frag col = srow (s), rows = o-quad mt*16+4g+j  -> coalesced 64B stores
        bool sv = srow < SB;
        int oq = mt * 16 + g * 4;
        if (sv) {
            size_t base = ((size_t)n * OO + oq) * (TT * VV) + (size_t)t0 * VV + srow;
            ypre[base              ] = y[0];
            ypre[base + 1 * TT * VV] = y[1];
            ypre[base + 2 * TT * VV] = y[2];
            ypre[base + 3 * TT * VV] = y[3];
        }
        float s1[4], s2[4];
#pragma unroll
        for (int j = 0; j < 4; ++j) {
            float v = sv ? y[j] : 0.0f;
            s1[j] = v;
            s2[j] = v * v;
        }
#pragma unroll
        for (int d = 1; d < 16; d <<= 1) {
#pragma unroll
            for (int j = 0; j < 4; ++j) {
                s1[j] += __shfl_xor(s1[j], d);
                s2[j] += __shfl_xor(s2[j], d);
            }
        }
        if (li == 0) {
#pragma unroll
            for (int j = 0; j < 4; ++j) {
                atomicAdd(&stats_s[oq + j], s1[j]);
                atomicAdd(&stats_s[64 + oq + j], s2[j]);
            }
        }
    }
    // NOTE: per-branch bias b.sum(0) is a per-channel constant -> exactly
    // cancelled by training-mode BN. Skipped on purpose (exact).

    __syncthreads();
    // Replicated global accumulation: ~38 blocks per replica slot -> negligible
    // same-line atomic serialization (vs 2400 blocks on one 512B buffer before).
    if (tid < 128) atomicAdd(&ws[(bid & (NREP - 1)) * 128 + tid], stats_s[tid]);
}

__global__ __launch_bounds__(256) void bn_relu(float* __restrict__ y,
                                               const float* __restrict__ stats,
                                               const float* __restrict__ gamma,
                                               const float* __restrict__ beta) {
    const int i4 = blockIdx.x * 256 + threadIdx.x;
    const size_t i = (size_t)i4 * 4;
    const int o = (int)((i / (TT * VV)) % OO);  // TT*VV=7500 divisible by 4

    const float cnt  = (float)NN * TT * VV;
    const float mean = stats[o] / cnt;
    const float var  = stats[OO + o] / cnt - mean * mean;
    const float inv  = rsqrtf(var + 1e-5f);
    const float sc   = gamma[o] * inv;
    const float sh   = beta[o] - mean * sc;

    float4 v = *reinterpret_cast<float4*>(y + i);
    v.x = fmaxf(v.x * sc + sh, 0.0f);
    v.y = fmaxf(v.y * sc + sh, 0.0f);
    v.z = fmaxf(v.z * sc + sh, 0.0f);
    v.w = fmaxf(v.w * sc + sh, 0.0f);
    *reinterpret_cast<float4*>(y + i) = v;
}

extern "C" void kernel_launch(void* const* d_in, const int* in_sizes, int n_in,
                              void* d_out, int out_size, void* d_ws, size_t ws_size,
                              hipStream_t stream) {
    const float* x     = (const float*)d_in[0];
    const float* A     = (const float*)d_in[1];
    const float* W     = (const float*)d_in[2];
    // d_in[3] = b : exactly cancelled by training-mode BN, unused
    const float* gamma = (const float*)d_in[4];
    const float* beta  = (const float*)d_in[5];
    float* out = (float*)d_out;
    float* ws  = (float*)d_ws;  // [0,8192): replica accumulators; [8192,8320): final stats

    hipLaunchKernelGGL(zero_stats, dim3(NREP * 128 / 256), dim3(256), 0, stream, ws);
    hipLaunchKernelGGL(gcn_main, dim3(NN * (TT / TB)), dim3(512), 0, stream,
                       x, A, W, out, ws);
    hipLaunchKernelGGL(reduce_stats, dim3(1), dim3(128), 0, stream, ws);
    hipLaunchKernelGGL(bn_relu, dim3((NN * OO * TT * VV) / 4 / 256), dim3(256), 0, stream,
                       out, ws + FINAL_OFF, gamma, beta);
}

// Round 6
// 92.889 us; speedup vs baseline: 3.3174x; 1.7126x over previous
//
#include <hip/hip_runtime.h>

// Sizes (fixed by the reference)
#define NN 32
#define CC 64
#define TT 300
#define VV 25
#define KK 3
#define OO 64
#define TB 4          // time steps per block
#define SB (TB * VV)  // 100 output spatial positions per block

// ws layout (floats): [0..128) = stats (sum, sumsq per channel)
//                     [128..128+6144) = Wpk: 1536 short8 W-fragments (24 KB)
//                     [6272..6272+1536) = Apk: 384 short8 A-fragments (6 KB)
#define WPK_OFF 128
#define APK_OFF (128 + 6144)

typedef __attribute__((ext_vector_type(8))) short short8;  // 8 bf16 = 4 VGPR
typedef __attribute__((ext_vector_type(4))) float f32x4;

// f32 -> bf16, round-to-nearest-even
__device__ __forceinline__ unsigned short f2bf(float f) {
    unsigned u = __builtin_bit_cast(unsigned, f);
    u += 0x7FFFu + ((u >> 16) & 1u);
    return (unsigned short)(u >> 16);
}

__global__ __launch_bounds__(128) void zero_stats(float* ws) {
    ws[threadIdx.x] = 0.0f;  // [0..63]=sum, [64..127]=sumsq
}

// One-time pack of W and A into the exact bf16 fragment layout the MFMA phases
// consume. Block-invariant work hoisted out of the 2400-block main kernel
// (was ~1250 VALU/thread of conversions re-done per block).
__global__ __launch_bounds__(512) void prep_pack(const float* __restrict__ A,
                                                 const float* __restrict__ W,
                                                 float* __restrict__ ws) {
    const int i = blockIdx.x * 512 + threadIdx.x;  // 0..2047, need 1920
    unsigned short* Wpk = reinterpret_cast<unsigned short*>(ws + WPK_OFF);
    unsigned short* Apk = reinterpret_cast<unsigned short*>(ws + APK_OFF);
    if (i < 1536) {
        // Wpk[mt][kap][lane] : A-operand frag, row o = mt*16+li, k-elems = kap*32+g*8+e
        int mt = i / 384, r = i - mt * 384;
        int kap = r / 64, lane = r - kap * 64;
        int li = lane & 15, g = lane >> 4;
        int o  = mt * 16 + li;
        int k  = kap >> 1, c0 = (kap & 1) * 32 + g * 8;
        const float* wp = W + ((size_t)(k * OO + o)) * CC + c0;
#pragma unroll
        for (int e = 0; e < 8; ++e) Wpk[i * 8 + e] = f2bf(wp[e]);
    } else if (i < 1920) {
        // Apk[k*2+nt][lane] : B-operand frag (A^T), col w = nt*16+li, k-elems v = g*8+e
        int j = i - 1536;
        int k = j / 128, r = j - k * 128;
        int nt = r / 64, lane = r - nt * 64;
        int li = lane & 15, g = lane >> 4;
        int w = nt * 16 + li;
#pragma unroll
        for (int e = 0; e < 8; ++e) {
            int v = g * 8 + e;
            float val = (v < VV && w < VV) ? A[(k * VV + v) * VV + w] : 0.0f;
            Apk[j * 8 + e] = f2bf(val);
        }
    }
}

// Block: (n, 4 time steps). 512 threads = 8 waves.
// Phase A: stage x[n,:,t0:t0+4,:] -> bf16 LDS x_s[row=t*64+c][v pad32] (swizzled)
// Phase B: GEMM1 (MFMA 16x16x32): xa[(t,c),w] = sum_v x*A_k  -> xa_s[s=t*25+w][kc=k*64+c]
// Phase C: GEMM2 (MFMA 16x16x32): y[o,s] = sum_kc W'[o,kc]*xa[kc,s] -> global
__global__ __launch_bounds__(512, 4) void gcn_main(const float* __restrict__ x,
                                                   const float* __restrict__ ws,
                                                   float* __restrict__ ypre) {
    __shared__ alignas(16) unsigned short x_s[256 * 32];    // 16 KB
    __shared__ alignas(16) unsigned short xa_s[112 * 192];  // 42 KB (rows 100..111 = pad,
                                                            // feed masked-out C columns only)

    const int bid  = blockIdx.x;
    const int n    = bid / (TT / TB);
    const int t0   = (bid % (TT / TB)) * TB;
    const int tid  = threadIdx.x;
    const int lane = tid & 63;
    const int wid  = tid >> 6;
    const int li   = lane & 15;   // fragment row/col index
    const int g    = lane >> 4;   // 16-lane group: k-elems = 8g..8g+7

    const unsigned short* Wpk = reinterpret_cast<const unsigned short*>(ws + WPK_OFF);
    const unsigned short* Apk = reinterpret_cast<const unsigned short*>(ws + APK_OFF);

    // ---- Phase A: stage x (coalesced float4 global, scalar bf16 LDS writes)
    const float* xg = x + (size_t)n * (CC * TT * VV) + (size_t)t0 * VV;
    for (int idx = tid; idx < CC * 25; idx += 512) {  // 1600 float4 = 100 f32 per channel
        int c = idx / 25, q = idx - c * 25;
        const float4 f = *reinterpret_cast<const float4*>(xg + (size_t)c * (TT * VV) + q * 4);
        float vals[4] = {f.x, f.y, f.z, f.w};
        int s0 = q * 4;
#pragma unroll
        for (int i = 0; i < 4; ++i) {
            int sp = s0 + i;               // may straddle the 25-joint boundary
            int t = sp / 25, v = sp - t * 25;
            int row = t * 64 + c;
            x_s[row * 32 + (v ^ (((row >> 1) & 3) << 3))] = f2bf(vals[i]);
        }
    }
    for (int idx = tid; idx < 256 * 7; idx += 512) {  // zero-fill K-pad v=25..31
        int row = idx / 7, v = 25 + (idx - row * 7);
        x_s[row * 32 + (v ^ (((row >> 1) & 3) << 3))] = 0;
    }

    // ---- A^T B-fragments: 6 coalesced 16B loads (pre-packed, replaces gather+convert)
    short8 afrag[6];
#pragma unroll
    for (int kn = 0; kn < 6; ++kn)
        afrag[kn] = *reinterpret_cast<const short8*>(Apk + ((size_t)kn * 64 + lane) * 8);

    __syncthreads();

    // ---- Phase B: GEMM1. M=(t*64+c) 256 rows = 16 Mtiles, N=w (2 tiles), K=32 (one MFMA)
#pragma unroll
    for (int k = 0; k < KK; ++k) {
        for (int mt = wid; mt < 16; mt += 8) {  // 2 Mtiles per wave per k
            int row = mt * 16 + li;
            const short8 xf = *reinterpret_cast<const short8*>(
                &x_s[row * 32 + ((g * 8) ^ (((row >> 1) & 3) << 3))]);
            f32x4 acc0 = {0.f, 0.f, 0.f, 0.f}, acc1 = {0.f, 0.f, 0.f, 0.f};
            acc0 = __builtin_amdgcn_mfma_f32_16x16x32_bf16(xf, afrag[k * 2 + 0], acc0, 0, 0, 0);
            acc1 = __builtin_amdgcn_mfma_f32_16x16x32_bf16(xf, afrag[k * 2 + 1], acc1, 0, 0, 0);
            // C-frag: col=li (w), rows = mt*16 + 4g + j  ->  t = row>>6, c-quad = row&63
            int r0 = mt * 16 + g * 4;
            int t = r0 >> 6, c0 = r0 & 63;
            int kc = k * 64 + c0;
            {
                int s = t * 25 + li;
                unsigned long long p =
                    (unsigned long long)f2bf(acc0[0]) |
                    ((unsigned long long)f2bf(acc0[1]) << 16) |
                    ((unsigned long long)f2bf(acc0[2]) << 32) |
                    ((unsigned long long)f2bf(acc0[3]) << 48);
                *reinterpret_cast<unsigned long long*>(
                    &xa_s[s * 192 + (kc ^ ((s & 7) << 3))]) = p;
            }
            int w1 = 16 + li;
            if (w1 < VV) {
                int s = t * 25 + w1;
                unsigned long long p =
                    (unsigned long long)f2bf(acc1[0]) |
                    ((unsigned long long)f2bf(acc1[1]) << 16) |
                    ((unsigned long long)f2bf(acc1[2]) << 32) |
                    ((unsigned long long)f2bf(acc1[3]) << 48);
                *reinterpret_cast<unsigned long long*>(
                    &xa_s[s * 192 + (kc ^ ((s & 7) << 3))]) = p;
            }
        }
    }

    __syncthreads();

    // ---- Phase C: GEMM2. M=o (4 Mtiles), N=s (7 Ntiles, last ragged), K=192 (6 steps)
    // W fragments come pre-packed from global (coalesced 1KB/wave/load, L1-resident).
    for (int u = wid; u < 28; u += 8) {
        int mt = u / 7, nt = u - mt * 7;
        int srow = nt * 16 + li;       // B-frag col = xa_s row
        const short8* wbase = reinterpret_cast<const short8*>(Wpk) + (size_t)(mt * 6) * 64 + lane;
        f32x4 y = {0.f, 0.f, 0.f, 0.f};
#pragma unroll
        for (int kap = 0; kap < 6; ++kap) {
            const short8 wf  = wbase[(size_t)kap * 64];
            const short8 xaf = *reinterpret_cast<const short8*>(
                &xa_s[srow * 192 + ((kap * 32 + g * 8) ^ ((srow & 7) << 3))]);
            y = __builtin_amdgcn_mfma_f32_16x16x32_bf16(wf, xaf, y, 0, 0, 0);
        }
        // epilogue: C-frag col = srow (s), rows = o-quad mt*16+4g+j  -> coalesced 64B stores
        if (srow < SB) {
            int oq = mt * 16 + g * 4;
            size_t base = ((size_t)n * OO + oq) * (TT * VV) + (size_t)t0 * VV + srow;
            ypre[base              ] = y[0];
            ypre[base + 1 * TT * VV] = y[1];
            ypre[base + 2 * TT * VV] = y[2];
            ypre[base + 3 * TT * VV] = y[3];
        }
    }
    // NOTE: per-branch bias b.sum(0) is a per-channel constant -> exactly
    // cancelled by training-mode BN. Skipped on purpose (exact).
}

// Per-channel sum / sumsq over ypre (L3-resident, bandwidth-bound).
__global__ __launch_bounds__(256) void stats_pass(const float* __restrict__ ypre,
                                                  float* __restrict__ ws) {
    __shared__ float red[8];
    const int bid = blockIdx.x;      // n*64 + o
    const int o   = bid & 63;
    const float4* p = reinterpret_cast<const float4*>(ypre + (size_t)bid * (TT * VV));
    float s1 = 0.0f, s2 = 0.0f;
    for (int i = threadIdx.x; i < (TT * VV) / 4; i += 256) {  // 1875 float4
        float4 v = p[i];
        s1 += v.x + v.y + v.z + v.w;
        s2 += v.x * v.x + v.y * v.y + v.z * v.z + v.w * v.w;
    }
#pragma unroll
    for (int d = 1; d < 64; d <<= 1) {
        s1 += __shfl_xor(s1, d);
        s2 += __shfl_xor(s2, d);
    }
    const int w = threadIdx.x >> 6;
    if ((threadIdx.x & 63) == 0) { red[w] = s1; red[4 + w] = s2; }
    __syncthreads();
    if (threadIdx.x == 0) {
        atomicAdd(&ws[o],      red[0] + red[1] + red[2] + red[3]);
        atomicAdd(&ws[64 + o], red[4] + red[5] + red[6] + red[7]);
    }
}

__global__ __launch_bounds__(256) void bn_relu(float* __restrict__ y,
                                               const float* __restrict__ stats,
                                               const float* __restrict__ gamma,
                                               const float* __restrict__ beta) {
    const int i4 = blockIdx.x * 256 + threadIdx.x;
    const size_t i = (size_t)i4 * 4;
    const int o = (int)((i / (TT * VV)) % OO);  // TT*VV=7500 divisible by 4

    const float cnt  = (float)NN * TT * VV;
    const float mean = stats[o] / cnt;
    const float var  = stats[OO + o] / cnt - mean * mean;
    const float inv  = rsqrtf(var + 1e-5f);
    const float sc   = gamma[o] * inv;
    const float sh   = beta[o] - mean * sc;

    float4 v = *reinterpret_cast<float4*>(y + i);
    v.x = fmaxf(v.x * sc + sh, 0.0f);
    v.y = fmaxf(v.y * sc + sh, 0.0f);
    v.z = fmaxf(v.z * sc + sh, 0.0f);
    v.w = fmaxf(v.w * sc + sh, 0.0f);
    *reinterpret_cast<float4*>(y + i) = v;
}

extern "C" void kernel_launch(void* const* d_in, const int* in_sizes, int n_in,
                              void* d_out, int out_size, void* d_ws, size_t ws_size,
                              hipStream_t stream) {
    const float* x     = (const float*)d_in[0];
    const float* A     = (const float*)d_in[1];
    const float* W     = (const float*)d_in[2];
    // d_in[3] = b : exactly cancelled by training-mode BN, unused
    const float* gamma = (const float*)d_in[4];
    const float* beta  = (const float*)d_in[5];
    float* out = (float*)d_out;
    float* ws  = (float*)d_ws;  // 31 KB used, see layout at top

    hipLaunchKernelGGL(zero_stats, dim3(1), dim3(128), 0, stream, ws);
    hipLaunchKernelGGL(prep_pack, dim3(4), dim3(512), 0, stream, A, W, ws);
    hipLaunchKernelGGL(gcn_main, dim3(NN * (TT / TB)), dim3(512), 0, stream,
                       x, ws, out);
    hipLaunchKernelGGL(stats_pass, dim3(NN * OO), dim3(256), 0, stream, out, ws);
    hipLaunchKernelGGL(bn_relu, dim3((NN * OO * TT * VV) / 4 / 256), dim3(256), 0, stream,
                       out, ws, gamma, beta);
}